// Round 1
// baseline (217.976 us; speedup 1.0000x reference)
//
#include <hip/hip_runtime.h>
#include <math.h>

#define Bq 4
#define Nq 128
#define Cq 256
#define HFq 23
#define WFq 30
#define PHq 7
#define PWq 7
#define HIDq 256
#define OUTq 5
#define Fq (Cq*PHq*PWq)      // 12544
#define Mq (Bq*Nq)           // 512
#define HWq (HFq*WFq)        // 690
#define SCALEq (1.0f/32.0f)
#define NEGq (-1e30f)
#define SPLITK 8
#define KCH (Fq/SPLITK)      // 1568
#define KSTEPS (KCH/32)      // 49

typedef float f32x4 __attribute__((ext_vector_type(4)));
typedef __bf16 bf16x8 __attribute__((ext_vector_type(8)));

__device__ __forceinline__ unsigned short f2b(float f) {
    unsigned int u = __float_as_uint(f);
    unsigned int r = (u + 0x7FFFu + ((u >> 16) & 1u)) >> 16;
    return (unsigned short)r;
}
__device__ __forceinline__ float b2f(unsigned short s) {
    return __uint_as_float(((unsigned int)s) << 16);
}

// K0a: transpose features (B,C,HF,WF) f32 -> (B, HF*WF, C) bf16
__global__ __launch_bounds__(256) void k_transpose(const float* __restrict__ feat,
                                                   unsigned short* __restrict__ ft) {
    __shared__ float t[32][33];
    int bb = blockIdx.z;
    const float* src = feat + (size_t)bb * Cq * HWq;
    unsigned short* dst = ft + (size_t)bb * HWq * Cq;
    int x0 = blockIdx.x * 32;      // HW dim
    int c0 = blockIdx.y * 32;      // C dim
    int tx = threadIdx.x, ty = threadIdx.y;
#pragma unroll
    for (int i = 0; i < 4; ++i) {
        int c = c0 + ty + i * 8;
        int x = x0 + tx;
        if (x < HWq) t[ty + i * 8][tx] = src[(size_t)c * HWq + x];
    }
    __syncthreads();
#pragma unroll
    for (int i = 0; i < 4; ++i) {
        int x = x0 + ty + i * 8;
        int c = c0 + tx;
        if (x < HWq) dst[(size_t)x * Cq + c] = f2b(t[tx][ty + i * 8]);
    }
}

// K0b: W1 f32 -> bf16
__global__ __launch_bounds__(256) void k_w1cvt(const float* __restrict__ W1,
                                               unsigned short* __restrict__ w1b) {
    int idx = blockIdx.x * 256 + threadIdx.x;
    // total = 3211264 floats = 802816 float4
    if (idx < 802816) {
        float4 v = ((const float4*)W1)[idx];
        ushort4 o;
        o.x = f2b(v.x); o.y = f2b(v.y); o.z = f2b(v.z); o.w = f2b(v.w);
        ((ushort4*)w1b)[idx] = o;
    }
}

// K1: ROI max pool. One block per (b,n), thread = channel.
__global__ __launch_bounds__(256) void k_pool(const unsigned short* __restrict__ ft,
                                              const float* __restrict__ props,
                                              unsigned short* __restrict__ pooled) {
    __shared__ __align__(16) unsigned short srow[Fq];
    int b = blockIdx.x >> 7;
    int n = blockIdx.x & 127;
    const float* pr = props + ((size_t)b * Nq + n) * 5;
    float b0 = pr[0] * SCALEq, b1v = pr[1] * SCALEq;
    float b2v = pr[2] * SCALEq, b3v = pr[3] * SCALEq;
    int x1 = min(max((int)floorf(b0), 0), WFq - 1);
    int y1 = min(max((int)floorf(b1v), 0), HFq - 1);
    int rw = min(max((int)ceilf(b2v) - x1, 1), WFq);
    int rh = min(max((int)ceilf(b3v) - y1, 1), HFq);
    const unsigned short* ftb = ft + (size_t)b * HWq * Cq;
    int c = threadIdx.x;
#pragma unroll
    for (int ph = 0; ph < PHq; ++ph) {
        int hs = y1 + (ph * rh) / PHq;
        int he = min(y1 + ((ph + 1) * rh + PHq - 1) / PHq, HFq);
#pragma unroll
        for (int pw = 0; pw < PWq; ++pw) {
            int wss = x1 + (pw * rw) / PWq;
            int wee = min(x1 + ((pw + 1) * rw + PWq - 1) / PWq, WFq);
            float acc = NEGq;
            for (int hh = hs; hh < he; ++hh) {
                const unsigned short* rowp = ftb + ((size_t)hh * WFq) * Cq + c;
                for (int ww = wss; ww < wee; ++ww) {
                    acc = fmaxf(acc, b2f(rowp[(size_t)ww * Cq]));
                }
            }
            srow[c * 49 + ph * 7 + pw] = f2b(acc);
        }
    }
    __syncthreads();
    const uint4* s4 = (const uint4*)srow;
    uint4* d4 = (uint4*)(pooled + (size_t)((size_t)b * Nq + n) * Fq);
    for (int i = threadIdx.x; i < Fq / 8; i += 256) d4[i] = s4[i];
}

// K2: GEMM1 with MFMA bf16: part[kz][m][j] = pooled[m,:] . W1[j,:] over K-chunk
__global__ __launch_bounds__(256) void k_gemm1(const unsigned short* __restrict__ pooled,
                                               const unsigned short* __restrict__ w1b,
                                               float* __restrict__ part) {
    __shared__ __align__(16) unsigned short As[64 * 32];
    __shared__ __align__(16) unsigned short Bs[64 * 32];
    int m0 = blockIdx.x * 64;
    int j0 = blockIdx.y * 64;
    int kz = blockIdx.z;
    int tid = threadIdx.x;
    int r = tid >> 2, qq = tid & 3;
    const uint4* ap = (const uint4*)(pooled + (size_t)(m0 + r) * Fq + (size_t)kz * KCH + qq * 8);
    const uint4* bp = (const uint4*)(w1b + (size_t)(j0 + r) * Fq + (size_t)kz * KCH + qq * 8);
    int lane = tid & 63, wv = tid >> 6;
    int q = lane >> 4, mr = lane & 15;
    f32x4 acc0 = {0.f, 0.f, 0.f, 0.f};
    f32x4 acc1 = {0.f, 0.f, 0.f, 0.f};
    f32x4 acc2 = {0.f, 0.f, 0.f, 0.f};
    f32x4 acc3 = {0.f, 0.f, 0.f, 0.f};
    const bf16x8* afp = (const bf16x8*)(As + (wv * 16 + mr) * 32 + q * 8);
    const bf16x8* bfp0 = (const bf16x8*)(Bs + (0 + mr) * 32 + q * 8);
    const bf16x8* bfp1 = (const bf16x8*)(Bs + (16 + mr) * 32 + q * 8);
    const bf16x8* bfp2 = (const bf16x8*)(Bs + (32 + mr) * 32 + q * 8);
    const bf16x8* bfp3 = (const bf16x8*)(Bs + (48 + mr) * 32 + q * 8);
    uint4* asw = (uint4*)(As + r * 32 + qq * 8);
    uint4* bsw = (uint4*)(Bs + r * 32 + qq * 8);
    for (int s = 0; s < KSTEPS; ++s) {
        uint4 av = ap[s * 4];
        uint4 bv = bp[s * 4];
        __syncthreads();
        *asw = av;
        *bsw = bv;
        __syncthreads();
        bf16x8 a = *afp;
        acc0 = __builtin_amdgcn_mfma_f32_16x16x32_bf16(a, *bfp0, acc0, 0, 0, 0);
        acc1 = __builtin_amdgcn_mfma_f32_16x16x32_bf16(a, *bfp1, acc1, 0, 0, 0);
        acc2 = __builtin_amdgcn_mfma_f32_16x16x32_bf16(a, *bfp2, acc2, 0, 0, 0);
        acc3 = __builtin_amdgcn_mfma_f32_16x16x32_bf16(a, *bfp3, acc3, 0, 0, 0);
    }
    float* pbase = part + (size_t)kz * Mq * HIDq;
    int mb = m0 + wv * 16 + q * 4;
    int jj = j0 + mr;
#pragma unroll
    for (int r2 = 0; r2 < 4; ++r2) {
        float* row = pbase + (size_t)(mb + r2) * HIDq + jj;
        row[0]  = acc0[r2];
        row[16] = acc1[r2];
        row[32] = acc2[r2];
        row[48] = acc3[r2];
    }
}

// K3: reduce split-K partials + bias + relu -> h
__global__ __launch_bounds__(256) void k_reduce(const float* __restrict__ part,
                                                const float* __restrict__ b1,
                                                float* __restrict__ h) {
    int m = blockIdx.x, j = threadIdx.x;
    float s = 0.f;
#pragma unroll
    for (int z = 0; z < SPLITK; ++z) s += part[((size_t)z * Mq + m) * HIDq + j];
    s += b1[j];
    h[(size_t)m * HIDq + j] = fmaxf(s, 0.f);
}

// K4: GEMM2 (512 x 5 x 256) + epilogue
__global__ __launch_bounds__(256) void k_final(const float* __restrict__ h,
                                               const float* __restrict__ W2,
                                               const float* __restrict__ b2,
                                               const float* __restrict__ props,
                                               float* __restrict__ out) {
    __shared__ float red[OUTq][4];
    int m = blockIdx.x, j = threadIdx.x;
    float hv = h[(size_t)m * HIDq + j];
    float p[OUTq];
#pragma unroll
    for (int o = 0; o < OUTq; ++o) p[o] = hv * W2[(size_t)o * HIDq + j];
    int lane = j & 63, wid = j >> 6;
#pragma unroll
    for (int o = 0; o < OUTq; ++o) {
        float v = p[o];
        v += __shfl_xor(v, 1);
        v += __shfl_xor(v, 2);
        v += __shfl_xor(v, 4);
        v += __shfl_xor(v, 8);
        v += __shfl_xor(v, 16);
        v += __shfl_xor(v, 32);
        if (lane == 0) red[o][wid] = v;
    }
    __syncthreads();
    if (j < OUTq) {
        float s = red[j][0] + red[j][1] + red[j][2] + red[j][3] + b2[j];
        float pv = props[(size_t)m * 5 + j];
        float r;
        if (j < 4) r = pv + s;
        else r = 1.f / (1.f + expf(-(pv + s)));
        out[(size_t)m * 5 + j] = r;
    }
}

extern "C" void kernel_launch(void* const* d_in, const int* in_sizes, int n_in,
                              void* d_out, int out_size, void* d_ws, size_t ws_size,
                              hipStream_t stream) {
    const float* feat  = (const float*)d_in[0];   // (4,256,23,30)
    const float* props = (const float*)d_in[1];   // (4,128,5)
    const float* W1    = (const float*)d_in[2];   // (256,12544)
    const float* b1    = (const float*)d_in[3];   // (256,)
    const float* W2    = (const float*)d_in[4];   // (5,256)
    const float* b2    = (const float*)d_in[5];   // (5,)
    float* out = (float*)d_out;

    char* ws = (char*)d_ws;
    unsigned short* ft     = (unsigned short*)(ws);             // 1,413,120 B
    unsigned short* w1b    = (unsigned short*)(ws + 1413120);   // 6,422,528 B
    unsigned short* pooled = (unsigned short*)(ws + 7835648);   // 12,845,056 B
    float* part            = (float*)(ws + 20680704);           // 4,194,304 B
    float* h               = (float*)(ws + 24875008);           // 524,288 B

    k_transpose<<<dim3(22, 8, 4), dim3(32, 8), 0, stream>>>(feat, ft);
    k_w1cvt<<<3136, 256, 0, stream>>>(W1, w1b);
    k_pool<<<512, 256, 0, stream>>>(ft, props, pooled);
    k_gemm1<<<dim3(8, 4, SPLITK), 256, 0, stream>>>(pooled, w1b, part);
    k_reduce<<<512, 256, 0, stream>>>(part, b1, h);
    k_final<<<512, 256, 0, stream>>>(h, W2, b2, props, out);
}

// Round 2
// 128.678 us; speedup vs baseline: 1.6940x; 1.6940x over previous
//
#include <hip/hip_runtime.h>
#include <math.h>

#define Bq 4
#define Nq 128
#define Cq 256
#define HFq 23
#define WFq 30
#define PHq 7
#define PWq 7
#define HIDq 256
#define OUTq 5
#define Fq (Cq*PHq*PWq)      // 12544
#define Mq (Bq*Nq)           // 512
#define HWq (HFq*WFq)        // 690
#define SCALEq (1.0f/32.0f)
#define NEGq (-1e30f)
#define KHq 5                // HF//PH + 2
#define KWq 6                // WF//PW + 2
#define SPLITK 14
#define KCH (Fq/SPLITK)      // 896
#define KSTEPS (KCH/32)      // 28

typedef float f32x4 __attribute__((ext_vector_type(4)));
typedef __bf16 bf16x8 __attribute__((ext_vector_type(8)));

__device__ __forceinline__ unsigned short f2b(float f) {
    unsigned int u = __float_as_uint(f);
    unsigned int r = (u + 0x7FFFu + ((u >> 16) & 1u)) >> 16;
    return (unsigned short)r;
}

// K0a: transpose features (B,C,HF,WF) f32 -> (B, HF*WF, C) f32
__global__ __launch_bounds__(256) void k_transpose(const float* __restrict__ feat,
                                                   float* __restrict__ ft) {
    __shared__ float t[32][33];
    int bb = blockIdx.z;
    const float* src = feat + (size_t)bb * Cq * HWq;
    float* dst = ft + (size_t)bb * HWq * Cq;
    int x0 = blockIdx.x * 32;      // HW dim
    int c0 = blockIdx.y * 32;      // C dim
    int tx = threadIdx.x, ty = threadIdx.y;
#pragma unroll
    for (int i = 0; i < 4; ++i) {
        int c = c0 + ty + i * 8;
        int x = x0 + tx;
        if (x < HWq) t[ty + i * 8][tx] = src[(size_t)c * HWq + x];
    }
    __syncthreads();
#pragma unroll
    for (int i = 0; i < 4; ++i) {
        int x = x0 + ty + i * 8;
        int c = c0 + tx;
        if (x < HWq) dst[(size_t)x * Cq + c] = t[tx][ty + i * 8];
    }
}

// K0b: W1 f32 (HID, c*49+cell) -> bf16 permuted to (HID, cell*256+c)
__global__ __launch_bounds__(256) void k_w1perm(const float* __restrict__ W1,
                                                unsigned short* __restrict__ w1p) {
    __shared__ __align__(16) unsigned short s[Fq];
    int j = blockIdx.x;
    const float4* src = (const float4*)(W1 + (size_t)j * Fq);
    for (int i = threadIdx.x; i < Fq / 4; i += 256) {
        float4 v = src[i];
        ushort4 o;
        o.x = f2b(v.x); o.y = f2b(v.y); o.z = f2b(v.z); o.w = f2b(v.w);
        ((ushort4*)s)[i] = o;
    }
    __syncthreads();
    uint4* dst = (uint4*)(w1p + (size_t)j * Fq);
    for (int i = threadIdx.x; i < Fq / 8; i += 256) {
        int base = i * 8;
        int cell = base >> 8;       // 8 consecutive c share one cell (256 % 8 == 0)
        int c0 = base & 255;
        unsigned short tmp[8];
#pragma unroll
        for (int u = 0; u < 8; ++u) tmp[u] = s[(c0 + u) * 49 + cell];
        dst[i] = *(const uint4*)tmp;
    }
}

// K1: ROI max pool. One wave per (proposal, cell-group). lane = 4 channels.
// Output layout: pooled[m][cell*256 + c] (cell-major), bf16.
__global__ __launch_bounds__(256) void k_pool(const float* __restrict__ ft,
                                              const float* __restrict__ props,
                                              unsigned short* __restrict__ pooled) {
    int wave = threadIdx.x >> 6;
    int lane = threadIdx.x & 63;
    int g = blockIdx.y * 4 + wave;   // cell group 0..7
    int m = blockIdx.x;              // proposal
    int b = m >> 7;
    const float* pr = props + (size_t)m * 5;
    float b0 = pr[0] * SCALEq, b1v = pr[1] * SCALEq;
    float b2v = pr[2] * SCALEq, b3v = pr[3] * SCALEq;
    int x1 = min(max((int)floorf(b0), 0), WFq - 1);
    int y1 = min(max((int)floorf(b1v), 0), HFq - 1);
    int rw = min(max((int)ceilf(b2v) - x1, 1), WFq);
    int rh = min(max((int)ceilf(b3v) - y1, 1), HFq);
    const float* ftb = ft + (size_t)b * HWq * Cq + lane * 4;
    unsigned short* pm = pooled + (size_t)m * Fq + lane * 4;

    for (int cell = g; cell < PHq * PWq; cell += 8) {
        int ph = cell / 7;
        int pw = cell - ph * 7;
        int hs = y1 + (ph * rh) / PHq;
        int he = min(y1 + ((ph + 1) * rh + PHq - 1) / PHq, HFq);
        int ws = x1 + (pw * rw) / PWq;
        int we = min(x1 + ((pw + 1) * rw + PWq - 1) / PWq, WFq);
        f32x4 acc = {NEGq, NEGq, NEGq, NEGq};
#pragma unroll
        for (int kh = 0; kh < KHq; ++kh) {
            if (hs + kh < he) {                      // wave-uniform
                const float* rowp = ftb + (size_t)((hs + kh) * WFq) * Cq;
#pragma unroll
                for (int kw = 0; kw < KWq; ++kw) {
                    if (ws + kw < we) {              // wave-uniform
                        f32x4 v = *(const f32x4*)(rowp + (size_t)(ws + kw) * Cq);
                        acc.x = fmaxf(acc.x, v.x);
                        acc.y = fmaxf(acc.y, v.y);
                        acc.z = fmaxf(acc.z, v.z);
                        acc.w = fmaxf(acc.w, v.w);
                    }
                }
            }
        }
        ushort4 o;
        o.x = f2b(acc.x); o.y = f2b(acc.y); o.z = f2b(acc.z); o.w = f2b(acc.w);
        *(ushort4*)(pm + (size_t)cell * Cq) = o;
    }
}

// K2: GEMM1 with MFMA bf16 + register prefetch pipeline.
__global__ __launch_bounds__(256) void k_gemm1(const unsigned short* __restrict__ pooled,
                                               const unsigned short* __restrict__ w1p,
                                               float* __restrict__ part) {
    __shared__ __align__(16) unsigned short As[64 * 32];
    __shared__ __align__(16) unsigned short Bs[64 * 32];
    int m0 = blockIdx.x * 64;
    int j0 = blockIdx.y * 64;
    int kz = blockIdx.z;
    int tid = threadIdx.x;
    int r = tid >> 2, qq = tid & 3;
    const uint4* ap = (const uint4*)(pooled + (size_t)(m0 + r) * Fq + (size_t)kz * KCH + qq * 8);
    const uint4* bp = (const uint4*)(w1p + (size_t)(j0 + r) * Fq + (size_t)kz * KCH + qq * 8);
    int lane = tid & 63, wv = tid >> 6;
    int q = lane >> 4, mr = lane & 15;
    f32x4 acc0 = {0.f, 0.f, 0.f, 0.f};
    f32x4 acc1 = {0.f, 0.f, 0.f, 0.f};
    f32x4 acc2 = {0.f, 0.f, 0.f, 0.f};
    f32x4 acc3 = {0.f, 0.f, 0.f, 0.f};
    const bf16x8* afp = (const bf16x8*)(As + (wv * 16 + mr) * 32 + q * 8);
    const bf16x8* bfp0 = (const bf16x8*)(Bs + (0 + mr) * 32 + q * 8);
    const bf16x8* bfp1 = (const bf16x8*)(Bs + (16 + mr) * 32 + q * 8);
    const bf16x8* bfp2 = (const bf16x8*)(Bs + (32 + mr) * 32 + q * 8);
    const bf16x8* bfp3 = (const bf16x8*)(Bs + (48 + mr) * 32 + q * 8);
    uint4* asw = (uint4*)(As + r * 32 + qq * 8);
    uint4* bsw = (uint4*)(Bs + r * 32 + qq * 8);
    uint4 av = ap[0];
    uint4 bv = bp[0];
    for (int s = 0; s < KSTEPS; ++s) {
        __syncthreads();
        *asw = av;
        *bsw = bv;
        __syncthreads();
        if (s + 1 < KSTEPS) {
            av = ap[(s + 1) * 4];
            bv = bp[(s + 1) * 4];
        }
        bf16x8 a = *afp;
        acc0 = __builtin_amdgcn_mfma_f32_16x16x32_bf16(a, *bfp0, acc0, 0, 0, 0);
        acc1 = __builtin_amdgcn_mfma_f32_16x16x32_bf16(a, *bfp1, acc1, 0, 0, 0);
        acc2 = __builtin_amdgcn_mfma_f32_16x16x32_bf16(a, *bfp2, acc2, 0, 0, 0);
        acc3 = __builtin_amdgcn_mfma_f32_16x16x32_bf16(a, *bfp3, acc3, 0, 0, 0);
    }
    float* pbase = part + (size_t)kz * Mq * HIDq;
    int mb = m0 + wv * 16 + q * 4;
    int jj = j0 + mr;
#pragma unroll
    for (int r2 = 0; r2 < 4; ++r2) {
        float* row = pbase + (size_t)(mb + r2) * HIDq + jj;
        row[0]  = acc0[r2];
        row[16] = acc1[r2];
        row[32] = acc2[r2];
        row[48] = acc3[r2];
    }
}

// K3: reduce split-K partials + bias + relu -> h
__global__ __launch_bounds__(256) void k_reduce(const float* __restrict__ part,
                                                const float* __restrict__ b1,
                                                float* __restrict__ h) {
    int m = blockIdx.x, j = threadIdx.x;
    float s = 0.f;
#pragma unroll
    for (int z = 0; z < SPLITK; ++z) s += part[((size_t)z * Mq + m) * HIDq + j];
    s += b1[j];
    h[(size_t)m * HIDq + j] = fmaxf(s, 0.f);
}

// K4: GEMM2 (512 x 5 x 256) + epilogue
__global__ __launch_bounds__(256) void k_final(const float* __restrict__ h,
                                               const float* __restrict__ W2,
                                               const float* __restrict__ b2,
                                               const float* __restrict__ props,
                                               float* __restrict__ out) {
    __shared__ float red[OUTq][4];
    int m = blockIdx.x, j = threadIdx.x;
    float hv = h[(size_t)m * HIDq + j];
    float p[OUTq];
#pragma unroll
    for (int o = 0; o < OUTq; ++o) p[o] = hv * W2[(size_t)o * HIDq + j];
    int lane = j & 63, wid = j >> 6;
#pragma unroll
    for (int o = 0; o < OUTq; ++o) {
        float v = p[o];
        v += __shfl_xor(v, 1);
        v += __shfl_xor(v, 2);
        v += __shfl_xor(v, 4);
        v += __shfl_xor(v, 8);
        v += __shfl_xor(v, 16);
        v += __shfl_xor(v, 32);
        if (lane == 0) red[o][wid] = v;
    }
    __syncthreads();
    if (j < OUTq) {
        float s = red[j][0] + red[j][1] + red[j][2] + red[j][3] + b2[j];
        float pv = props[(size_t)m * 5 + j];
        float r;
        if (j < 4) r = pv + s;
        else r = 1.f / (1.f + expf(-(pv + s)));
        out[(size_t)m * 5 + j] = r;
    }
}

extern "C" void kernel_launch(void* const* d_in, const int* in_sizes, int n_in,
                              void* d_out, int out_size, void* d_ws, size_t ws_size,
                              hipStream_t stream) {
    const float* feat  = (const float*)d_in[0];   // (4,256,23,30)
    const float* props = (const float*)d_in[1];   // (4,128,5)
    const float* W1    = (const float*)d_in[2];   // (256,12544)
    const float* b1    = (const float*)d_in[3];   // (256,)
    const float* W2    = (const float*)d_in[4];   // (5,256)
    const float* b2    = (const float*)d_in[5];   // (5,)
    float* out = (float*)d_out;

    char* ws = (char*)d_ws;
    float* ft              = (float*)(ws);                       // 2,826,240 B
    unsigned short* w1p    = (unsigned short*)(ws + 2826240);    // 6,422,528 B
    unsigned short* pooled = (unsigned short*)(ws + 9248768);    // 12,845,056 B
    float* part            = (float*)(ws + 22093824);            // 7,340,032 B
    float* h               = (float*)(ws + 29433856);            // 524,288 B  -> 29,958,144 total

    k_transpose<<<dim3(22, 8, 4), dim3(32, 8), 0, stream>>>(feat, ft);
    k_w1perm<<<HIDq, 256, 0, stream>>>(W1, w1p);
    k_pool<<<dim3(Mq, 2), 256, 0, stream>>>(ft, props, pooled);
    k_gemm1<<<dim3(8, 4, SPLITK), 256, 0, stream>>>(pooled, w1p, part);
    k_reduce<<<Mq, 256, 0, stream>>>(part, b1, h);
    k_final<<<Mq, 256, 0, stream>>>(h, W2, b2, props, out);
}